// Round 11
// baseline (3077.314 us; speedup 1.0000x reference)
//
#include <hip/hip_runtime.h>
#include <math.h>

#define N      100   // nodes per problem
#define D      128   // embedding dim = H*DKH
#define KL     10    // prefix length
#define S0     90    // unvisited slots (fixed)
#define STEPS  90
#define LDK    132   // LDS row stride (floats); odd float4 count
#define NT     512

__device__ __forceinline__ float dot4(float4 a, float4 b) {
  return a.x*b.x + a.y*b.y + a.z*b.z + a.w*b.w;
}
__device__ __forceinline__ void fma4(float4& acc, float a, float4 v) {
  acc.x += a*v.x; acc.y += a*v.y; acc.z += a*v.z; acc.w += a*v.w;
}

// Rows [base, base+cnt) of E@W (col-major W) or Wcomb (row-major) -> stage[row*LDK+col].
// grp = tid>>7 is WAVE-UNIFORM -> nd[] in SGPRs, enc row loads are scalar loads.
template<int RPT>
__device__ __forceinline__ void cc(const float* __restrict__ encB,
                                   const float* __restrict__ W,
                                   bool wRowMajor, int base, int cnt,
                                   const int* __restrict__ slotNode,
                                   float* __restrict__ stage, int tid) {
  const int col = tid & 127;
  const int grp = tid >> 7;
  float acc[RPT];
  int   nd [RPT];
  #pragma unroll
  for (int ii = 0; ii < RPT; ++ii) {
    acc[ii] = 0.f;
    int r = grp + 4*ii;
    nd[ii] = (r < cnt) ? __builtin_amdgcn_readfirstlane(slotNode[base + r]) : 0;
  }
  for (int dd = 0; dd < D; dd += 16) {
    float w[16];
    #pragma unroll
    for (int t = 0; t < 16; ++t)
      w[t] = wRowMajor ? W[col*D + dd + t] : W[(dd+t)*D + col];
    #pragma unroll
    for (int ii = 0; ii < RPT; ++ii) {
      int r = grp + 4*ii;
      if (r < cnt) {
        const float* er = encB + (size_t)nd[ii]*D + dd;
        float a0=0,a1=0,a2=0,a3=0;
        #pragma unroll
        for (int t = 0; t < 16; t += 4) {
          a0 += er[t]*w[t];   a1 += er[t+1]*w[t+1];
          a2 += er[t+2]*w[t+2]; a3 += er[t+3]*w[t+3];
        }
        acc[ii] += (a0+a1)+(a2+a3);
      }
    }
  }
  #pragma unroll
  for (int ii = 0; ii < RPT; ++ii) {
    int r = grp + 4*ii;
    if (r < cnt) stage[(base + r)*LDK + col] = acc[ii];
  }
}

// ccq: same staging but stores acc + bias[col] (bias = q1 row). Col-major W.
// Same per-row FP order as cc + the old readback add (acc + q1[col]).
template<int RPT>
__device__ __forceinline__ void ccq(const float* __restrict__ encB,
                                    const float* __restrict__ W,
                                    int base, int cnt,
                                    const int* __restrict__ slotNode,
                                    const float* __restrict__ bias,
                                    float* __restrict__ stage, int tid) {
  const int col = tid & 127;
  const int grp = tid >> 7;
  float acc[RPT];
  int   nd [RPT];
  #pragma unroll
  for (int ii = 0; ii < RPT; ++ii) {
    acc[ii] = 0.f;
    int r = grp + 4*ii;
    nd[ii] = (r < cnt) ? __builtin_amdgcn_readfirstlane(slotNode[base + r]) : 0;
  }
  for (int dd = 0; dd < D; dd += 16) {
    float w[16];
    #pragma unroll
    for (int t = 0; t < 16; ++t) w[t] = W[(dd+t)*D + col];
    #pragma unroll
    for (int ii = 0; ii < RPT; ++ii) {
      int r = grp + 4*ii;
      if (r < cnt) {
        const float* er = encB + (size_t)nd[ii]*D + dd;
        float a0=0,a1=0,a2=0,a3=0;
        #pragma unroll
        for (int t = 0; t < 16; t += 4) {
          a0 += er[t]*w[t];   a1 += er[t+1]*w[t+1];
          a2 += er[t+2]*w[t+2]; a3 += er[t+3]*w[t+3];
        }
        acc[ii] += (a0+a1)+(a2+a3);
      }
    }
  }
  const float bq = bias[col];
  #pragma unroll
  for (int ii = 0; ii < RPT; ++ii) {
    int r = grp + 4*ii;
    if (r < cnt) stage[(base + r)*LDK + col] = acc[ii] + bq;
  }
}

__global__ __launch_bounds__(NT, 4)   // 4 waves/EU -> <=128 VGPR
void policy_kernel(const float* __restrict__ enc,
                   const float* __restrict__ Wq_first,
                   const float* __restrict__ Wq_last,
                   const float* __restrict__ Wk,
                   const float* __restrict__ Wv,
                   const float* __restrict__ Wcomb,
                   const int*   __restrict__ prefix,
                   int*         __restrict__ out) {
  // ---- LDS ~49 KB ----
  // sQ: staging buffer for K,V,CE passes; FINAL home of the 91 q-rows
  // (rows 0..89 = slot q-rows, row 90 = last0's initial q), q1 pre-added.
  // CE lives in REGISTERS during decode (ce[8] per thread, static per step).
  __shared__ __align__(16) float sQ[(S0+1)*LDK];
  __shared__ __align__(16) float sMh[D];       // q1 scratch (plain idx), then
                                               // normalized mh, SWIZZLED layout
  __shared__ int   sSlotNode[96];
  __shared__ unsigned long long sPacked[2];    // double-buffered argmax
  __shared__ int   sLast0;

  const int tid = threadIdx.x;
  const int b   = blockIdx.x;
  const float* encB = enc + (size_t)b*N*D;

  // ---- init ----
  if (tid < KL) out[(size_t)b*N + tid] = prefix[b*KL + tid];
  if (tid == 0) {
    unsigned vis[4] = {0u,0u,0u,0u};
    const int* pr = prefix + b*KL;
    for (int j = 0; j < KL; ++j) { int n = pr[j]; vis[n>>5] |= 1u << (n&31); }
    int cnt = 0;
    for (int n = 0; n < N; ++n)
      if (!((vis[n>>5] >> (n&31)) & 1u)) sSlotNode[cnt++] = n;
    sLast0 = pr[KL-1];
    sSlotNode[S0] = pr[KL-1];                  // row 90's node for ccq
    sPacked[0] = 0ull; sPacked[1] = 0ull;
  }
  __syncthreads();

  // ---- q1 = enc[last0] @ Wq_first -> sMh (scratch, plain indexing) ----
  if (tid < D) {
    const int last0 = sLast0;
    const float* er = encB + (size_t)last0*D;
    float a0=0,a1=0,a2=0,a3=0;
    #pragma unroll
    for (int d = 0; d < D; d += 4) {
      a0 += er[d]  *Wq_first[d*D     + tid];
      a1 += er[d+1]*Wq_first[(d+1)*D + tid];
      a2 += er[d+2]*Wq_first[(d+2)*D + tid];
      a3 += er[d+3]*Wq_first[(d+3)*D + tid];
    }
    sMh[tid] = (a0+a1)+(a2+a3);
  }
  __syncthreads();

  const int h = tid >> 6, l = tid & 63;

  // ---- K pass: stage all 90 rows, load per-lane fragments ----
  cc<23>(encB, Wk, false, 0, S0, sSlotNode, sQ, tid);
  __syncthreads();
  float4 ka0,ka1,ka2,ka3, kb0,kb1,kb2,kb3;
  {
    const float* p = &sQ[l*LDK + h*16];
    ka0 = *(const float4*)(p+0);  ka1 = *(const float4*)(p+4);
    ka2 = *(const float4*)(p+8);  ka3 = *(const float4*)(p+12);
  }
  if (l < 26) {
    const float* p = &sQ[(64+l)*LDK + h*16];
    kb0 = *(const float4*)(p+0);  kb1 = *(const float4*)(p+4);
    kb2 = *(const float4*)(p+8);  kb3 = *(const float4*)(p+12);
  } else {
    kb0=kb1=kb2=kb3 = make_float4(0.f,0.f,0.f,0.f);
  }
  __syncthreads();

  // ---- V pass: stage, load per-thread fragments ----
  const int cQuad = tid >> 4;   // 0..31 (output quad)
  const int cStrm = tid & 15;   // slot stream
  cc<12>(encB, Wv, false,  0, 48, sSlotNode, sQ, tid);
  cc<12>(encB, Wv, false, 48, 42, sSlotNode, sQ, tid);
  __syncthreads();
  float4 v0,v1,v2,v3,v4,v5;
  v0 = *(const float4*)&sQ[(cStrm     )*LDK + cQuad*4];
  v1 = *(const float4*)&sQ[(cStrm + 16)*LDK + cQuad*4];
  v2 = *(const float4*)&sQ[(cStrm + 32)*LDK + cQuad*4];
  v3 = *(const float4*)&sQ[(cStrm + 48)*LDK + cQuad*4];
  v4 = *(const float4*)&sQ[(cStrm + 64)*LDK + cQuad*4];
  v5 = (cStrm < 10) ? *(const float4*)&sQ[(cStrm + 80)*LDK + cQuad*4]
                    : make_float4(0.f,0.f,0.f,0.f);
  __syncthreads();

  // ---- CE pass: stage, then HOIST each D-thread's 32 floats to registers ----
  cc<6>(encB, Wcomb, true,  0, 24, sSlotNode, sQ, tid);
  cc<6>(encB, Wcomb, true, 24, 24, sSlotNode, sQ, tid);
  cc<6>(encB, Wcomb, true, 48, 24, sSlotNode, sQ, tid);
  cc<6>(encB, Wcomb, true, 72, 18, sSlotNode, sQ, tid);
  __syncthreads();
  const int di  = tid >> 2;    // phase D slot
  const int dkc = tid & 3;     // phase D k-chunk
  float4 ce[8];
  if (tid < 384) {
    #pragma unroll
    for (int j = 0; j < 8; ++j)
      ce[j] = *(const float4*)&sQ[di*LDK + dkc*32 + j*4];
  } else {
    #pragma unroll
    for (int j = 0; j < 8; ++j) ce[j] = make_float4(0.f,0.f,0.f,0.f);
  }
  __syncthreads();   // CE regs captured before q-build overwrites sQ

  // ---- Q pass (LAST -> survives into decode): rows 0..90, q1 pre-added ----
  ccq<12>(encB, Wq_last,  0, 48, sSlotNode, sMh, sQ, tid);
  ccq<12>(encB, Wq_last, 48, 43, sSlotNode, sMh, sQ, tid);   // incl. row 90
  __syncthreads();

  // ---- decode: 90 steps, TWO barriers/step.
  //      B reads the winner q-row DIRECTLY from sQ[cur] (broadcast) — no
  //      qp select chain, no sq round-trip. D's CE comes from registers —
  //      no CE LDS reads (and no dkc*32 bank conflicts).
  int   cur  = S0;             // current q row (row 90 = last0)
  float visA = 0.f, visB = 0.f, visD = 0.f;

  for (int step = 0; step < STEPS; ++step) {
    // B: scores vs register K; exp (wave-local, pure registers, no reduce)
    float x0, x1;
    {
      const float* qr = &sQ[cur*LDK + h*16];   // wave-uniform broadcast read
      const float4 q0 = *(const float4*)(qr + 0);
      const float4 q1 = *(const float4*)(qr + 4);
      const float4 q2 = *(const float4*)(qr + 8);
      const float4 q3 = *(const float4*)(qr + 12);
      float s0 = dot4(q0,ka0)+dot4(q1,ka1)+dot4(q2,ka2)+dot4(q3,ka3);
      x0 = expf(s0*0.25f + visA);
      x1 = 0.f;
      if (l < 26) {
        float s1 = dot4(q0,kb0)+dot4(q1,kb1)+dot4(q2,kb2)+dot4(q3,kb3);
        x1 = expf(s1*0.25f + visB);
      }
    }

    // C: mh from register V; att pulled from B's regs via shfl.
    //    s_loc rides the same butterfly -> per-head partition sum for free.
    {
      const float a0 = __shfl(x0, cStrm);
      const float a1 = __shfl(x0, cStrm + 16);
      const float a2 = __shfl(x0, cStrm + 32);
      const float a3 = __shfl(x0, cStrm + 48);
      const float a4 = __shfl(x1, cStrm);
      const float a5 = __shfl(x1, cStrm + 16);
      float s_loc = (a0+a1)+(a2+a3)+(a4+a5);
      float4 acc = make_float4(0.f,0.f,0.f,0.f);
      fma4(acc, a0, v0);
      fma4(acc, a1, v1);
      fma4(acc, a2, v2);
      fma4(acc, a3, v3);
      fma4(acc, a4, v4);
      fma4(acc, a5, v5);      // v5=0 for cStrm>=10
      #pragma unroll
      for (int off = 1; off < 16; off <<= 1) {
        acc.x += __shfl_xor(acc.x, off);
        acc.y += __shfl_xor(acc.y, off);
        acc.z += __shfl_xor(acc.z, off);
        acc.w += __shfl_xor(acc.w, off);
        s_loc += __shfl_xor(s_loc, off);
      }
      if (cStrm == 0) {
        const float r = 1.0f / s_loc;               // per-head normalization
        float4 o; o.x=acc.x*r; o.y=acc.y*r; o.z=acc.z*r; o.w=acc.w*r;
        *(float4*)&sMh[((cQuad & 7) << 4) + ((cQuad >> 3) << 2)] = o;
      }
    }
    __syncthreads();                               // BAR1: sMh complete

    // Reset NEXT step's argmax buffer (readers/writers fenced by BAR1/BAR2).
    if (tid == NT-1) sPacked[(step+1)&1] = 0ull;

    // D: sc[i] = mh . CE_regs[i]; argmax -> packed atomicMax
    if (tid < 384) {
      float a = 0.f;
      #pragma unroll
      for (int j = 0; j < 8; ++j) {
        const float4 mh = *(const float4*)&sMh[j*16 + dkc*4];   // swizzled
        a += dot4(ce[j], mh);
      }
      a += __shfl_xor(a, 1);
      a += __shfl_xor(a, 2);
      float val = (di < S0) ? a + visD : -INFINITY;
      int   idx = (di < S0) ? di : 127;
      // quad-replicated -> 4 stages (offsets 1,2 would compare identical pairs)
      #pragma unroll
      for (int off = 4; off <= 32; off <<= 1) {
        float ov = __shfl_xor(val, off);
        int   oi = __shfl_xor(idx, off);
        if (ov > val || (ov == val && oi < idx)) { val = ov; idx = oi; }
      }
      if (l == 0) {
        unsigned s = __float_as_uint(val);
        s = (s & 0x80000000u) ? ~s : (s | 0x80000000u);
        unsigned long long pk = ((unsigned long long)s << 32)
                              | (unsigned long long)(unsigned)(127 - idx);
        atomicMax(&sPacked[step&1], pk);
      }
    }
    __syncthreads();                               // BAR2: winner complete

    // A: read winner; write out; update vis; set cur (no LDS publish needed)
    {
      const unsigned long long u = sPacked[step & 1];
      const int idx = __builtin_amdgcn_readfirstlane(127 - (int)(u & 0xFFull));
      if (tid == 0) out[(size_t)b*N + KL + step] = sSlotNode[idx];
      if (idx == l)      visA = -INFINITY;
      if (idx == l + 64) visB = -INFINITY;
      if (idx == di)     visD = -INFINITY;
      cur = idx;
    }
    // no barrier: next B reads static sQ rows; only `cur` changed (register)
  }
}

extern "C" void kernel_launch(void* const* d_in, const int* in_sizes, int n_in,
                              void* d_out, int out_size, void* d_ws, size_t ws_size,
                              hipStream_t stream) {
  // inputs: 0 problems (unused), 1 encoded_nodes f32, 2 Wq_first, 3 Wq_last,
  //         4 Wk, 5 Wv, 6 Wcomb, 7 prefix i32
  const float* enc      = (const float*)d_in[1];
  const float* Wq_first = (const float*)d_in[2];
  const float* Wq_last  = (const float*)d_in[3];
  const float* Wk       = (const float*)d_in[4];
  const float* Wv       = (const float*)d_in[5];
  const float* Wcomb    = (const float*)d_in[6];
  const int*   prefix   = (const int*)d_in[7];
  const int batch = in_sizes[7] / KL;   // 2048
  policy_kernel<<<batch, NT, 0, stream>>>(enc, Wq_first, Wq_last, Wk, Wv, Wcomb,
                                          prefix, (int*)d_out);
}

// Round 12
// 2510.315 us; speedup vs baseline: 1.2259x; 1.2259x over previous
//
#include <hip/hip_runtime.h>
#include <math.h>

#define N      100   // nodes per problem
#define D      128   // embedding dim = H*DKH
#define KL     10    // prefix length
#define S0     90    // unvisited slots (fixed)
#define STEPS  90
#define LDK    132   // LDS row stride (floats); odd float4 count
#define NT     512

__device__ __forceinline__ float dot4(float4 a, float4 b) {
  return a.x*b.x + a.y*b.y + a.z*b.z + a.w*b.w;
}
__device__ __forceinline__ void fma4(float4& acc, float a, float4 v) {
  acc.x += a*v.x; acc.y += a*v.y; acc.z += a*v.z; acc.w += a*v.w;
}

// Rows [base, base+cnt) of E@W (col-major W) or Wcomb (row-major) -> stage[row*LDK+col].
// grp = tid>>7 is WAVE-UNIFORM -> nd[] in SGPRs, enc row loads are scalar loads.
template<int RPT>
__device__ __forceinline__ void cc(const float* __restrict__ encB,
                                   const float* __restrict__ W,
                                   bool wRowMajor, int base, int cnt,
                                   const int* __restrict__ slotNode,
                                   float* __restrict__ stage, int tid) {
  const int col = tid & 127;
  const int grp = tid >> 7;
  float acc[RPT];
  int   nd [RPT];
  #pragma unroll
  for (int ii = 0; ii < RPT; ++ii) {
    acc[ii] = 0.f;
    int r = grp + 4*ii;
    nd[ii] = (r < cnt) ? __builtin_amdgcn_readfirstlane(slotNode[base + r]) : 0;
  }
  for (int dd = 0; dd < D; dd += 16) {
    float w[16];
    #pragma unroll
    for (int t = 0; t < 16; ++t)
      w[t] = wRowMajor ? W[col*D + dd + t] : W[(dd+t)*D + col];
    #pragma unroll
    for (int ii = 0; ii < RPT; ++ii) {
      int r = grp + 4*ii;
      if (r < cnt) {
        const float* er = encB + (size_t)nd[ii]*D + dd;
        float a0=0,a1=0,a2=0,a3=0;
        #pragma unroll
        for (int t = 0; t < 16; t += 4) {
          a0 += er[t]*w[t];   a1 += er[t+1]*w[t+1];
          a2 += er[t+2]*w[t+2]; a3 += er[t+3]*w[t+3];
        }
        acc[ii] += (a0+a1)+(a2+a3);
      }
    }
  }
  #pragma unroll
  for (int ii = 0; ii < RPT; ++ii) {
    int r = grp + 4*ii;
    if (r < cnt) stage[(base + r)*LDK + col] = acc[ii];
  }
}

// ccq: same staging but stores acc + bias[col] (bias = q1 row). Col-major W.
// Per-row FP order identical to cc + the q1 add. SMALL RPT: this pass runs
// with 88 persistent VGPRs live (K,V,CE frags) — RPT=4 keeps peak < 128
// (round-11 lesson: ccq<12> here spilled ce[] to scratch, +19GB HBM traffic).
template<int RPT>
__device__ __forceinline__ void ccq(const float* __restrict__ encB,
                                    const float* __restrict__ W,
                                    int base, int cnt,
                                    const int* __restrict__ slotNode,
                                    const float* __restrict__ bias,
                                    float* __restrict__ stage, int tid) {
  const int col = tid & 127;
  const int grp = tid >> 7;
  float acc[RPT];
  int   nd [RPT];
  #pragma unroll
  for (int ii = 0; ii < RPT; ++ii) {
    acc[ii] = 0.f;
    int r = grp + 4*ii;
    nd[ii] = (r < cnt) ? __builtin_amdgcn_readfirstlane(slotNode[base + r]) : 0;
  }
  for (int dd = 0; dd < D; dd += 16) {
    float w[16];
    #pragma unroll
    for (int t = 0; t < 16; ++t) w[t] = W[(dd+t)*D + col];
    #pragma unroll
    for (int ii = 0; ii < RPT; ++ii) {
      int r = grp + 4*ii;
      if (r < cnt) {
        const float* er = encB + (size_t)nd[ii]*D + dd;
        float a0=0,a1=0,a2=0,a3=0;
        #pragma unroll
        for (int t = 0; t < 16; t += 4) {
          a0 += er[t]*w[t];   a1 += er[t+1]*w[t+1];
          a2 += er[t+2]*w[t+2]; a3 += er[t+3]*w[t+3];
        }
        acc[ii] += (a0+a1)+(a2+a3);
      }
    }
  }
  const float bq = bias[col];
  #pragma unroll
  for (int ii = 0; ii < RPT; ++ii) {
    int r = grp + 4*ii;
    if (r < cnt) stage[(base + r)*LDK + col] = acc[ii] + bq;
  }
}

__global__ __launch_bounds__(NT, 4)   // 4 waves/EU -> <=128 VGPR
void policy_kernel(const float* __restrict__ enc,
                   const float* __restrict__ Wq_first,
                   const float* __restrict__ Wq_last,
                   const float* __restrict__ Wk,
                   const float* __restrict__ Wv,
                   const float* __restrict__ Wcomb,
                   const int*   __restrict__ prefix,
                   int*         __restrict__ out) {
  // ---- LDS ~49 KB ----
  // sQ: staging buffer for K,V,CE passes; FINAL home of the 91 q-rows
  // (rows 0..89 = slot q-rows, row 90 = last0's initial q), q1 pre-added.
  // CE lives in REGISTERS during decode (ce[8] per thread, static per step).
  __shared__ __align__(16) float sQ[(S0+1)*LDK];
  __shared__ __align__(16) float sMh[D];       // q1 scratch (plain idx), then
                                               // normalized mh, SWIZZLED layout
  __shared__ int   sSlotNode[96];
  __shared__ unsigned long long sPacked[2];    // double-buffered argmax
  __shared__ int   sLast0;

  const int tid = threadIdx.x;
  const int b   = blockIdx.x;
  const float* encB = enc + (size_t)b*N*D;

  // ---- init ----
  if (tid < KL) out[(size_t)b*N + tid] = prefix[b*KL + tid];
  if (tid == 0) {
    unsigned vis[4] = {0u,0u,0u,0u};
    const int* pr = prefix + b*KL;
    for (int j = 0; j < KL; ++j) { int n = pr[j]; vis[n>>5] |= 1u << (n&31); }
    int cnt = 0;
    for (int n = 0; n < N; ++n)
      if (!((vis[n>>5] >> (n&31)) & 1u)) sSlotNode[cnt++] = n;
    sLast0 = pr[KL-1];
    sSlotNode[S0] = pr[KL-1];                  // row 90's node for ccq
    sPacked[0] = 0ull; sPacked[1] = 0ull;
  }
  __syncthreads();

  // ---- q1 = enc[last0] @ Wq_first -> sMh (scratch, plain indexing) ----
  if (tid < D) {
    const int last0 = sLast0;
    const float* er = encB + (size_t)last0*D;
    float a0=0,a1=0,a2=0,a3=0;
    #pragma unroll
    for (int d = 0; d < D; d += 4) {
      a0 += er[d]  *Wq_first[d*D     + tid];
      a1 += er[d+1]*Wq_first[(d+1)*D + tid];
      a2 += er[d+2]*Wq_first[(d+2)*D + tid];
      a3 += er[d+3]*Wq_first[(d+3)*D + tid];
    }
    sMh[tid] = (a0+a1)+(a2+a3);
  }
  __syncthreads();

  const int h = tid >> 6, l = tid & 63;

  // ---- K pass: stage all 90 rows, load per-lane fragments ----
  cc<23>(encB, Wk, false, 0, S0, sSlotNode, sQ, tid);
  __syncthreads();
  float4 ka0,ka1,ka2,ka3, kb0,kb1,kb2,kb3;
  {
    const float* p = &sQ[l*LDK + h*16];
    ka0 = *(const float4*)(p+0);  ka1 = *(const float4*)(p+4);
    ka2 = *(const float4*)(p+8);  ka3 = *(const float4*)(p+12);
  }
  if (l < 26) {
    const float* p = &sQ[(64+l)*LDK + h*16];
    kb0 = *(const float4*)(p+0);  kb1 = *(const float4*)(p+4);
    kb2 = *(const float4*)(p+8);  kb3 = *(const float4*)(p+12);
  } else {
    kb0=kb1=kb2=kb3 = make_float4(0.f,0.f,0.f,0.f);
  }
  __syncthreads();

  // ---- V pass: stage, load per-thread fragments ----
  const int cQuad = tid >> 4;   // 0..31 (output quad)
  const int cStrm = tid & 15;   // slot stream
  cc<12>(encB, Wv, false,  0, 48, sSlotNode, sQ, tid);
  cc<12>(encB, Wv, false, 48, 42, sSlotNode, sQ, tid);
  __syncthreads();
  float4 v0,v1,v2,v3,v4,v5;
  v0 = *(const float4*)&sQ[(cStrm     )*LDK + cQuad*4];
  v1 = *(const float4*)&sQ[(cStrm + 16)*LDK + cQuad*4];
  v2 = *(const float4*)&sQ[(cStrm + 32)*LDK + cQuad*4];
  v3 = *(const float4*)&sQ[(cStrm + 48)*LDK + cQuad*4];
  v4 = *(const float4*)&sQ[(cStrm + 64)*LDK + cQuad*4];
  v5 = (cStrm < 10) ? *(const float4*)&sQ[(cStrm + 80)*LDK + cQuad*4]
                    : make_float4(0.f,0.f,0.f,0.f);
  __syncthreads();

  // ---- CE pass: stage, then HOIST each D-thread's 32 floats to registers ----
  cc<6>(encB, Wcomb, true,  0, 24, sSlotNode, sQ, tid);
  cc<6>(encB, Wcomb, true, 24, 24, sSlotNode, sQ, tid);
  cc<6>(encB, Wcomb, true, 48, 24, sSlotNode, sQ, tid);
  cc<6>(encB, Wcomb, true, 72, 18, sSlotNode, sQ, tid);
  __syncthreads();
  const int di  = tid >> 2;    // phase D slot
  const int dkc = tid & 3;     // phase D k-chunk
  float4 ce[8];
  if (tid < 384) {
    #pragma unroll
    for (int j = 0; j < 8; ++j)
      ce[j] = *(const float4*)&sQ[di*LDK + dkc*32 + j*4];
  } else {
    #pragma unroll
    for (int j = 0; j < 8; ++j) ce[j] = make_float4(0.f,0.f,0.f,0.f);
  }
  __syncthreads();   // CE regs captured before q-build overwrites sQ

  // ---- Q pass (LAST -> survives into decode): rows 0..90, q1 pre-added.
  //      RPT=4 x 6 calls: low working set on top of 88 live VGPRs (no spill).
  ccq<4>(encB, Wq_last,  0, 16, sSlotNode, sMh, sQ, tid);
  ccq<4>(encB, Wq_last, 16, 16, sSlotNode, sMh, sQ, tid);
  ccq<4>(encB, Wq_last, 32, 16, sSlotNode, sMh, sQ, tid);
  ccq<4>(encB, Wq_last, 48, 16, sSlotNode, sMh, sQ, tid);
  ccq<4>(encB, Wq_last, 64, 16, sSlotNode, sMh, sQ, tid);
  ccq<4>(encB, Wq_last, 80, 11, sSlotNode, sMh, sQ, tid);   // incl. row 90
  __syncthreads();

  // ---- decode: 90 steps, TWO barriers/step.
  //      B reads the winner q-row DIRECTLY from sQ[cur] (broadcast) — no
  //      qp select chain, no sq round-trip. D's CE comes from registers —
  //      no CE LDS reads (and no dkc*32 bank conflicts).
  int   cur  = S0;             // current q row (row 90 = last0)
  float visA = 0.f, visB = 0.f, visD = 0.f;

  for (int step = 0; step < STEPS; ++step) {
    // B: scores vs register K; exp (wave-local, pure registers, no reduce)
    float x0, x1;
    {
      const float* qr = &sQ[cur*LDK + h*16];   // wave-uniform broadcast read
      const float4 q0 = *(const float4*)(qr + 0);
      const float4 q1 = *(const float4*)(qr + 4);
      const float4 q2 = *(const float4*)(qr + 8);
      const float4 q3 = *(const float4*)(qr + 12);
      float s0 = dot4(q0,ka0)+dot4(q1,ka1)+dot4(q2,ka2)+dot4(q3,ka3);
      x0 = expf(s0*0.25f + visA);
      x1 = 0.f;
      if (l < 26) {
        float s1 = dot4(q0,kb0)+dot4(q1,kb1)+dot4(q2,kb2)+dot4(q3,kb3);
        x1 = expf(s1*0.25f + visB);
      }
    }

    // C: mh from register V; att pulled from B's regs via shfl.
    //    s_loc rides the same butterfly -> per-head partition sum for free.
    {
      const float a0 = __shfl(x0, cStrm);
      const float a1 = __shfl(x0, cStrm + 16);
      const float a2 = __shfl(x0, cStrm + 32);
      const float a3 = __shfl(x0, cStrm + 48);
      const float a4 = __shfl(x1, cStrm);
      const float a5 = __shfl(x1, cStrm + 16);
      float s_loc = (a0+a1)+(a2+a3)+(a4+a5);
      float4 acc = make_float4(0.f,0.f,0.f,0.f);
      fma4(acc, a0, v0);
      fma4(acc, a1, v1);
      fma4(acc, a2, v2);
      fma4(acc, a3, v3);
      fma4(acc, a4, v4);
      fma4(acc, a5, v5);      // v5=0 for cStrm>=10
      #pragma unroll
      for (int off = 1; off < 16; off <<= 1) {
        acc.x += __shfl_xor(acc.x, off);
        acc.y += __shfl_xor(acc.y, off);
        acc.z += __shfl_xor(acc.z, off);
        acc.w += __shfl_xor(acc.w, off);
        s_loc += __shfl_xor(s_loc, off);
      }
      if (cStrm == 0) {
        const float r = 1.0f / s_loc;               // per-head normalization
        float4 o; o.x=acc.x*r; o.y=acc.y*r; o.z=acc.z*r; o.w=acc.w*r;
        *(float4*)&sMh[((cQuad & 7) << 4) + ((cQuad >> 3) << 2)] = o;
      }
    }
    __syncthreads();                               // BAR1: sMh complete

    // Reset NEXT step's argmax buffer (readers/writers fenced by BAR1/BAR2).
    if (tid == NT-1) sPacked[(step+1)&1] = 0ull;

    // D: sc[i] = mh . CE_regs[i]; argmax -> packed atomicMax
    if (tid < 384) {
      float a = 0.f;
      #pragma unroll
      for (int j = 0; j < 8; ++j) {
        const float4 mh = *(const float4*)&sMh[j*16 + dkc*4];   // swizzled
        a += dot4(ce[j], mh);
      }
      a += __shfl_xor(a, 1);
      a += __shfl_xor(a, 2);
      float val = (di < S0) ? a + visD : -INFINITY;
      int   idx = (di < S0) ? di : 127;
      // quad-replicated -> 4 stages (offsets 1,2 would compare identical pairs)
      #pragma unroll
      for (int off = 4; off <= 32; off <<= 1) {
        float ov = __shfl_xor(val, off);
        int   oi = __shfl_xor(idx, off);
        if (ov > val || (ov == val && oi < idx)) { val = ov; idx = oi; }
      }
      if (l == 0) {
        unsigned s = __float_as_uint(val);
        s = (s & 0x80000000u) ? ~s : (s | 0x80000000u);
        unsigned long long pk = ((unsigned long long)s << 32)
                              | (unsigned long long)(unsigned)(127 - idx);
        atomicMax(&sPacked[step&1], pk);
      }
    }
    __syncthreads();                               // BAR2: winner complete

    // A: read winner; write out; update vis; set cur (no LDS publish needed)
    {
      const unsigned long long u = sPacked[step & 1];
      const int idx = __builtin_amdgcn_readfirstlane(127 - (int)(u & 0xFFull));
      if (tid == 0) out[(size_t)b*N + KL + step] = sSlotNode[idx];
      if (idx == l)      visA = -INFINITY;
      if (idx == l + 64) visB = -INFINITY;
      if (idx == di)     visD = -INFINITY;
      cur = idx;
    }
    // no barrier: next B reads static sQ rows; only `cur` changed (register)
  }
}

extern "C" void kernel_launch(void* const* d_in, const int* in_sizes, int n_in,
                              void* d_out, int out_size, void* d_ws, size_t ws_size,
                              hipStream_t stream) {
  // inputs: 0 problems (unused), 1 encoded_nodes f32, 2 Wq_first, 3 Wq_last,
  //         4 Wk, 5 Wv, 6 Wcomb, 7 prefix i32
  const float* enc      = (const float*)d_in[1];
  const float* Wq_first = (const float*)d_in[2];
  const float* Wq_last  = (const float*)d_in[3];
  const float* Wk       = (const float*)d_in[4];
  const float* Wv       = (const float*)d_in[5];
  const float* Wcomb    = (const float*)d_in[6];
  const int*   prefix   = (const int*)d_in[7];
  const int batch = in_sizes[7] / KL;   // 2048
  policy_kernel<<<batch, NT, 0, stream>>>(enc, Wq_first, Wq_last, Wk, Wv, Wcomb,
                                          prefix, (int*)d_out);
}